// Round 10
// baseline (476.338 us; speedup 1.0000x reference)
//
#include <hip/hip_runtime.h>
#include <hip/hip_cooperative_groups.h>
#include <cstdint>
#include <cstddef>

typedef __bf16 bf16x8 __attribute__((ext_vector_type(8)));
typedef float f32x4 __attribute__((ext_vector_type(4)));

__device__ __forceinline__ float bf2f(unsigned short u){
  unsigned int x = ((unsigned int)u) << 16;
  return __builtin_bit_cast(float, x);
}
__device__ __forceinline__ unsigned short f2bf(float f){
  unsigned int x = __builtin_bit_cast(unsigned int, f);
  x += 0x7fffu + ((x >> 16) & 1u);
  return (unsigned short)(x >> 16);
}

// ---- cross-lane reductions on the (idle) LDS pipe: ds_swizzle butterflies ----
template<int P> __device__ __forceinline__ float swz_add(float x){
  int y = __builtin_amdgcn_ds_swizzle(__builtin_bit_cast(int, x), P);
  return x + __builtin_bit_cast(float, y);
}
__device__ __forceinline__ float sum16(float x){
  x = swz_add<0x041F>(x);   // xor 1  (BitMode: and=0x1F, or=0, xor=k)
  x = swz_add<0x081F>(x);   // xor 2
  x = swz_add<0x101F>(x);   // xor 4
  x = swz_add<0x201F>(x);   // xor 8
  return x;
}
__device__ __forceinline__ float sum64(float x, int bpa){
  x = swz_add<0x041F>(x);
  x = swz_add<0x081F>(x);
  x = swz_add<0x101F>(x);
  x = swz_add<0x201F>(x);
  x = swz_add<0x401F>(x);   // xor 16 (within 32-lane group)
  int y = __builtin_amdgcn_ds_bpermute(bpa, __builtin_bit_cast(int, x)); // lane^32
  return x + __builtin_bit_cast(float, y);
}

__device__ __forceinline__ float load_w(const void* ew, int e, int f){
  return f ? ((const float*)ew)[e] : bf2f(((const unsigned short*)ew)[e]);
}

// fixed-point packing for the 64b atomic (per-XCD replica):
//   acc[d*NREP + rep] += (1<<40) | round(w * 2^24)
// high 24 bits = replica count (old>>40 == replica-local rank), low 40 = wsum.
// NOTE (r5/r7/r8/r9): padding, addr-sharding, MLPx4, XCD replicas ALL null ->
// ~12 G returning-RMW/s is the memory-side atomic floor. Build path closed.
#define WSUM_MASK  ((1ull << 40) - 1ull)
#define WSUM_SCALE 16777216.0f
#define WSUM_INV   (1.0f / 16777216.0f)
#define NREP 8

// ---------------- mega canon kernel ----------------
// [r10] xc canon DELETED: gemm0 reads x directly (flag-branched load),
// removing ~6250 blocks and 25.6 MB of traffic from this launch.
// Block ranges: [0] params+flag; [1,321) weight transpose; [321,..) acc zero.

struct MegaArgs {
  const void* psrc[15]; float* pdst[15]; int pn[15]; float pscale[15];
  const void* wsrc[6]; unsigned short* wdst[6]; int wM[6];
  const void* x;
  int* cnt; int nz4;
  int* flag;
};

__global__ __launch_bounds__(256) void k_mega(MegaArgs a){
  __shared__ int sf;
  if (threadIdx.x == 0) sf = 0;
  __syncthreads();
  {
    unsigned short u = ((const unsigned short*)a.x)[threadIdx.x];
    int expo = (u >> 7) & 0xFF;
    if (expo >= 0xC0) atomicOr(&sf, 1);
  }
  __syncthreads();
  int f = sf;
  int b = blockIdx.x;

  if (b == 0){
    if (threadIdx.x == 0) a.flag[0] = f;
    for (int t = 0; t < 15; t++){
      int i = threadIdx.x;
      if (i < a.pn[t]){
        float v = f ? ((const float*)a.psrc[t])[i]
                    : bf2f(((const unsigned short*)a.psrc[t])[i]);
        a.pdst[t][i] = v * a.pscale[t];
      }
    }
    return;
  }
  b -= 1;
  if (b < 320){
    int t, base;
    if      (b <  64){ t = 0; base = b;       }
    else if (b < 128){ t = 1; base = b - 64;  }
    else if (b < 192){ t = 2; base = b - 128; }
    else if (b < 256){ t = 3; base = b - 192; }
    else if (b < 288){ t = 4; base = b - 256; }
    else             { t = 5; base = b - 288; }
    int M = a.wM[t];
    int idx = base*256 + threadIdx.x;
    if (idx < 128*M){
      int k = idx / M, m2 = idx % M;
      unsigned short v = f ? f2bf(((const float*)a.wsrc[t])[idx])
                           : ((const unsigned short*)a.wsrc[t])[idx];
      a.wdst[t][m2*128 + k] = v;
    }
    return;
  }
  b -= 320;
  int i = b*256 + threadIdx.x;
  if (i < a.nz4) ((int4*)a.cnt)[i] = make_int4(0, 0, 0, 0);
}

// ---------------- fused: layer-0 GEMM (reads x directly) + hist ----------------
// blocks [0, gB): gemm layer-0 (4 row-tile waves per block, L+R halves);
// blocks [gB, ..): hist, 1 edge/thread, replica = blockIdx & 7.

__global__ __launch_bounds__(256) void k_histgemm(
  const void* __restrict__ X,
  const unsigned short* __restrict__ WTl, const unsigned short* __restrict__ WTr,
  const float* __restrict__ bl, const float* __restrict__ br,
  unsigned short* __restrict__ outL, float* __restrict__ outR,
  int nrows, int rowBlocks, int gB,
  const int* __restrict__ ei, const void* __restrict__ ew,
  unsigned long long* __restrict__ acc,
  int* __restrict__ rank, int E, int n, const int* __restrict__ flag)
{
  int b = blockIdx.x;
  if (b < gB){
    int wid = threadIdx.x >> 6;
    int t = b*4 + wid;
    if (t >= 2*rowBlocks) return;
    bool isR = t >= rowBlocks;
    int r0 = (isR ? t - rowBlocks : t) * 16;
    const unsigned short* WT = isR ? WTr : WTl;
    const float* bia         = isR ? br  : bl;
    int lane = threadIdx.x & 63;
    int q = lane >> 4, rr = lane & 15;
    int xf = flag[0];

    f32x4 ac[8];
    #pragma unroll
    for (int c = 0; c < 8; c++) ac[c] = (f32x4){0.f, 0.f, 0.f, 0.f};
    int row = r0 + rr;
    if (row >= nrows) row = nrows - 1;
    #pragma unroll
    for (int kc = 0; kc < 4; kc++){
      bf16x8 af;
      if (xf){
        const float* xp = (const float*)X + (size_t)row*128 + kc*32 + q*8;
        float4 lo = *(const float4*)xp;
        float4 hi = *(const float4*)(xp + 4);
        unsigned short t8[8] = { f2bf(lo.x), f2bf(lo.y), f2bf(lo.z), f2bf(lo.w),
                                 f2bf(hi.x), f2bf(hi.y), f2bf(hi.z), f2bf(hi.w) };
        __builtin_memcpy(&af, t8, 16);
      } else {
        af = *(const bf16x8*)((const unsigned short*)X + (size_t)row*128 + kc*32 + q*8);
      }
      #pragma unroll
      for (int ct = 0; ct < 8; ct++){
        bf16x8 bfr = *(const bf16x8*)(WT + (size_t)(ct*16 + rr)*128 + kc*32 + q*8);
        ac[ct] = __builtin_amdgcn_mfma_f32_16x16x32_bf16(af, bfr, ac[ct], 0, 0, 0);
      }
    }
    #pragma unroll
    for (int ct = 0; ct < 8; ct++){
      int col = ct*16 + rr;
      float bv = bia[col];
      #pragma unroll
      for (int t4 = 0; t4 < 4; t4++){
        int orow = r0 + q*4 + t4;
        if (orow < nrows){
          float v = ac[ct][t4] + bv;
          if (isR) outR[(size_t)orow*128 + col] = v;
          else     outL[(size_t)orow*128 + col] = f2bf(v);
        }
      }
    }
    return;
  }
  int e = (b - gB)*256 + threadIdx.x;
  if (e < E){
    int d = ei[E + e];
    int r = 0;
    if ((unsigned)d < (unsigned)n){
      float w = load_w(ew, e, flag[0]);
      unsigned int wq = (unsigned int)(w * WSUM_SCALE + 0.5f);
      unsigned long long pk = (1ull << 40) | (unsigned long long)wq;
      int rep = b & (NREP - 1);    // == ((e>>8) + gB) & 7, recomputed in scatter
      unsigned long long old = atomicAdd(&acc[(size_t)d*NREP + rep], pk);
      r = (int)(old >> 40);
    }
    rank[e] = r;
  }
}

// ---------------- cooperative fused scan (phases 1+2+3 in one launch) ----------------
// phase A == old k_scan1 (per-block degree sums); grid.sync(); phase B == old
// k_scan3 (inline bsum prefix + block scan + pso emit). nB blocks co-resident.

__global__ void k_scanc(const unsigned long long* __restrict__ acc,
                        int* __restrict__ bsum,
                        int* __restrict__ rowptr, uint4* __restrict__ pso,
                        int n, int nB){
  __shared__ int ws[4];
  __shared__ int sboff;
  int tid = threadIdx.x;
  int lane = tid & 63, w = tid >> 6;
  int i = blockIdx.x*256 + tid;

  // ---- phase A: block sum of (deg+1) ----
  {
    int v = 0;
    if (i < n){
      const unsigned long long* a = acc + (size_t)i*NREP;
      int s = 0;
      #pragma unroll
      for (int r = 0; r < NREP; r++) s += (int)(a[r] >> 40);
      v = s + 1;
    }
    for (int off = 32; off; off >>= 1) v += __shfl_down(v, off);
    if (lane == 0) ws[w] = v;
    __syncthreads();
    if (tid == 0) bsum[blockIdx.x] = ws[0] + ws[1] + ws[2] + ws[3];
  }
  cooperative_groups::this_grid().sync();

  // ---- phase B: inline prefix of bsum[0..b) + block-local scan + pso ----
  int part = 0;
  for (int t = tid; t < blockIdx.x; t += 256) part += bsum[t];
  for (int off = 32; off; off >>= 1) part += __shfl_down(part, off);
  __syncthreads();   // ws reuse guard
  if (lane == 0) ws[w] = part;
  __syncthreads();
  if (tid == 0) sboff = ws[0] + ws[1] + ws[2] + ws[3];
  __syncthreads();
  int boff = sboff;
  __syncthreads();

  int v = 0;
  if (i < n){
    const unsigned long long* a = acc + (size_t)i*NREP;
    int c[NREP], s = 0;
    unsigned short pf[NREP];
    #pragma unroll
    for (int r = 0; r < NREP; r++){
      c[r] = (int)(a[r] >> 40);
      pf[r] = (unsigned short)s;
      s += c[r];
    }
    v = s + 1;
    uint4 o;
    o.x = (unsigned)pf[0] | ((unsigned)pf[1] << 16);
    o.y = (unsigned)pf[2] | ((unsigned)pf[3] << 16);
    o.z = (unsigned)pf[4] | ((unsigned)pf[5] << 16);
    o.w = (unsigned)pf[6] | ((unsigned)pf[7] << 16);
    pso[i] = o;
  }
  int sv = v;
  for (int off = 1; off < 64; off <<= 1){
    int t = __shfl_up(sv, off);
    if (lane >= off) sv += t;
  }
  if (lane == 63) ws[w] = sv;
  __syncthreads();
  if (tid == 0){
    int acc2 = 0;
    for (int k = 0; k < 4; k++){ int t = ws[k]; ws[k] = acc2; acc2 += t; }
  }
  __syncthreads();
  if (i < n) rowptr[i + 1] = boff + ws[w] + sv;
  if (i == 0) rowptr[0] = 0;
  (void)nB;
}

// fused: ATOMIC-FREE scatter (blocks [0,Eb)) + self-loop write (blocks [Eb,..)).
// pos = rowptr[d] + replicaPrefix[d][rep] + replica-local rank,
// rep = ((e>>8) + gB) & 7 (same formula as hist).
__global__ void k_scat_self(const int* __restrict__ ei, const void* __restrict__ ew,
                            const int* __restrict__ rank, const int* __restrict__ rowptr,
                            const unsigned long long* __restrict__ acc,
                            const uint4* __restrict__ pso,
                            uint2* __restrict__ csr,
                            int E, int n, int ET, const int* __restrict__ flag,
                            int Eb, int gB){
  int b = blockIdx.x;
  if (b < Eb){
    int e = b*256 + threadIdx.x;
    if (e < E){
      int s = ei[e], d = ei[E + e];
      if ((unsigned)d < (unsigned)n){
        int rep = ((e >> 8) + gB) & (NREP - 1);
        uint4 ps = pso[d];
        unsigned word = (rep < 4) ? ((rep < 2) ? ps.x : ps.y)
                                  : ((rep < 6) ? ps.z : ps.w);
        unsigned pref = (word >> ((rep & 1) * 16)) & 0xffffu;
        int pos = rowptr[d] + (int)pref + rank[e];
        if ((unsigned)pos < (unsigned)ET){
          float w = load_w(ew, e, flag[0]);
          csr[pos] = make_uint2((unsigned)s, __builtin_bit_cast(unsigned, w));
        }
      }
    }
  } else {
    int i = (b - Eb)*256 + threadIdx.x;
    if (i < n){
      int beg = rowptr[i], endv = rowptr[i+1];
      int deg = endv - 1 - beg;
      const unsigned long long* a = acc + (size_t)i*NREP;
      unsigned long long s = 0;
      #pragma unroll
      for (int r = 0; r < NREP; r++) s += (a[r] & WSUM_MASK);
      float ws = (float)s * WSUM_INV;
      float w = ws / fmaxf((float)deg, 1.0f);
      csr[endv - 1] = make_uint2((unsigned)i, __builtin_bit_cast(unsigned, w));
    }
  }
}

// ---------------- GEMM (layers 1,2): xl (bf16) and xr (f32) in one launch ----------------

template<int NC>
__global__ __launch_bounds__(64) void k_gemm2(
  const unsigned short* __restrict__ A,
  const unsigned short* __restrict__ WTl, const unsigned short* __restrict__ WTr,
  const float* __restrict__ bl, const float* __restrict__ br,
  unsigned short* __restrict__ outL, float* __restrict__ outR,
  int nrows)
{
  constexpr int CT = NC / 16;
  int lane = threadIdx.x;
  int q = lane >> 4, rr = lane & 15;
  int r0 = blockIdx.x * 16;
  bool isR = blockIdx.y == 1;
  const unsigned short* WT = isR ? WTr : WTl;
  const float* bia         = isR ? br  : bl;

  f32x4 acc[CT];
  #pragma unroll
  for (int b = 0; b < CT; b++) acc[b] = (f32x4){0.f, 0.f, 0.f, 0.f};

  int row = r0 + rr;
  if (row >= nrows) row = nrows - 1;

  #pragma unroll
  for (int kc = 0; kc < 4; kc++){
    bf16x8 af = *(const bf16x8*)(A + (size_t)row*128 + kc*32 + q*8);
    #pragma unroll
    for (int ct = 0; ct < CT; ct++){
      bf16x8 bfr = *(const bf16x8*)(WT + (size_t)(ct*16 + rr)*128 + kc*32 + q*8);
      acc[ct] = __builtin_amdgcn_mfma_f32_16x16x32_bf16(af, bfr, acc[ct], 0, 0, 0);
    }
  }

  // C/D layout: col = lane&15, row = (lane>>4)*4 + reg
  #pragma unroll
  for (int ct = 0; ct < CT; ct++){
    int col = ct*16 + rr;
    float bv = bia[col];
    #pragma unroll
    for (int t = 0; t < 4; t++){
      int orow = r0 + q*4 + t;
      if (orow < nrows){
        float v = acc[ct][t] + bv;
        if (isR) outR[(size_t)orow*NC + col] = v;
        else     outL[(size_t)orow*NC + col] = f2bf(v);
      }
    }
  }
}

// ---------------- fused edge scoring + online-softmax aggregation ----------------
// [round-3/5 proven bodies] readfirstlane-scalarized csr fetch, |t| leakyrelu
// fold, ds_swizzle reductions, 8-edge SGPR block prefetch.

__global__ __launch_bounds__(256) void k_edge128(
  const unsigned short* __restrict__ xl, const float* __restrict__ xr,
  const int* __restrict__ rowptr, const uint2* __restrict__ csr,
  const float* __restrict__ We, const float* __restrict__ att,
  const float* __restrict__ bias, unsigned short* __restrict__ out, int n, int ET)
{
  int wid = threadIdx.x >> 6;
  int lane = threadIdx.x & 63;
  int node = __builtin_amdgcn_readfirstlane(blockIdx.x*4 + wid);
  if (node >= n) return;
  int ch = lane*2;
  float we0 = We[ch],  we1 = We[ch+1];
  float at0 = att[ch], at1 = att[ch+1];   // pre-scaled by log2e
  float c10 = 0.6f*at0, c20 = 0.4f*at0;
  float c11 = 0.6f*at1, c21 = 0.4f*at1;
  float2 xrv = *(const float2*)(xr + (size_t)node*128 + ch);
  float fxr0 = xrv.x, fxr1 = xrv.y;
  int beg = rowptr[node], end = rowptr[node+1];
  if (beg < 0) beg = 0;
  if (end > ET) end = ET;
  float m = -1e30f, l = 0.f, a0 = 0.f, a1 = 0.f;

  auto loadblk = [&](int base, int* S, float* W){
    #pragma unroll
    for (int j = 0; j < 8; j++){
      uint2 pk = csr[base + j];          // uniform addr -> s_load
      int sv = (int)pk.x;
      if ((unsigned)sv >= (unsigned)n) sv = 0;
      S[j] = sv;
      W[j] = __builtin_bit_cast(float, pk.y);
    }
  };

  int i = beg;
  int sc_[8]; float wc_[8];
  bool have = (i + 8 <= end);
  if (have) loadblk(i, sc_, wc_);
  while (have){
    unsigned u[8];
    #pragma unroll
    for (int j = 0; j < 8; j++){
      const unsigned short* rp = xl + (size_t)sc_[j]*128;   // scalar base
      u[j] = *(const unsigned int*)(rp + ch);               // saddr + v_ch
    }
    bool hnext = (i + 16 <= end);
    int sn_[8]; float wn_[8];
    if (hnext) loadblk(i + 8, sn_, wn_);    // prefetch next block

    float vx[8], vy[8], pp[8];
    #pragma unroll
    for (int j = 0; j < 8; j++){
      vx[j] = __builtin_bit_cast(float, u[j] << 16);
      vy[j] = __builtin_bit_cast(float, u[j] & 0xffff0000u);
      float t0 = fmaf(wc_[j], we0, fxr0) + vx[j];
      float t1 = fmaf(wc_[j], we1, fxr1) + vy[j];
      float p  = fmaf(c10, t0, c20*fabsf(t0));
      p        = fmaf(c11, t1, fmaf(c21, fabsf(t1), p));
      pp[j] = sum16(p);
    }
    float mx = fmaxf(fmaxf(fmaxf(pp[0], pp[1]), fmaxf(pp[2], pp[3])),
                     fmaxf(fmaxf(pp[4], pp[5]), fmaxf(pp[6], pp[7])));
    float nm = fmaxf(m, mx);
    float sc = exp2f(m - nm);
    float el = 0.f, ea0 = 0.f, ea1 = 0.f;
    #pragma unroll
    for (int j = 0; j < 8; j++){
      float e = exp2f(pp[j] - nm);
      el  += e;
      ea0 += e*vx[j];
      ea1 += e*vy[j];
    }
    l  = l*sc  + el;
    a0 = a0*sc + ea0;
    a1 = a1*sc + ea1;
    m = nm;
    i += 8;
    have = hnext;
    if (have){
      #pragma unroll
      for (int j = 0; j < 8; j++){ sc_[j] = sn_[j]; wc_[j] = wn_[j]; }
    }
  }
  for (; i < end; i++){
    uint2 pk = csr[i];
    int sv = (int)pk.x;
    if ((unsigned)sv >= (unsigned)n) sv = 0;
    float w = __builtin_bit_cast(float, pk.y);
    const unsigned short* rp = xl + (size_t)sv*128;
    unsigned u = *(const unsigned int*)(rp + ch);
    float x0 = __builtin_bit_cast(float, u << 16);
    float x1 = __builtin_bit_cast(float, u & 0xffff0000u);
    float t0 = fmaf(w, we0, fxr0) + x0;
    float t1 = fmaf(w, we1, fxr1) + x1;
    float p  = fmaf(c10, t0, c20*fabsf(t0));
    p        = fmaf(c11, t1, fmaf(c21, fabsf(t1), p));
    p = sum16(p);
    float nm = fmaxf(m, p);
    float scv = exp2f(m - nm);
    float pe  = exp2f(p - nm);
    l  = l*scv  + pe;
    a0 = a0*scv + pe*x0;
    a1 = a1*scv + pe*x1;
    m = nm;
  }
  float inv = 1.0f / (l + 1e-16f);
  float o0 = a0*inv + bias[ch];
  float o1 = a1*inv + bias[ch+1];
  o0 = o0 > 0.f ? o0 : (__expf(o0) - 1.0f);   // ELU (layers 0,1)
  o1 = o1 > 0.f ? o1 : (__expf(o1) - 1.0f);
  unsigned int packed = (unsigned int)f2bf(o0) | ((unsigned int)f2bf(o1) << 16);
  *(unsigned int*)(out + (size_t)node*128 + ch) = packed;
}

__global__ __launch_bounds__(256) void k_edge64(
  const unsigned short* __restrict__ xl, const float* __restrict__ xr,
  const int* __restrict__ rowptr, const uint2* __restrict__ csr,
  const float* __restrict__ We, const float* __restrict__ att,
  const float* __restrict__ bias, void* __restrict__ out, int n, int ET,
  const int* __restrict__ flag)
{
  int wid = threadIdx.x >> 6;
  int lane = threadIdx.x & 63;
  int node = __builtin_amdgcn_readfirstlane(blockIdx.x*4 + wid);
  if (node >= n) return;
  float we0 = We[lane];
  float at0 = att[lane];          // pre-scaled by log2e
  float c1 = 0.6f*at0, c2 = 0.4f*at0;
  float fxr0 = xr[(size_t)node*64 + lane];
  int bpa = ((lane ^ 32) << 2);
  int beg = rowptr[node], end = rowptr[node+1];
  if (beg < 0) beg = 0;
  if (end > ET) end = ET;
  float m = -1e30f, l = 0.f, a0 = 0.f;

  auto loadblk = [&](int base, int* S, float* W){
    #pragma unroll
    for (int j = 0; j < 8; j++){
      uint2 pk = csr[base + j];
      int sv = (int)pk.x;
      if ((unsigned)sv >= (unsigned)n) sv = 0;
      S[j] = sv;
      W[j] = __builtin_bit_cast(float, pk.y);
    }
  };

  int i = beg;
  int sc_[8]; float wc_[8];
  bool have = (i + 8 <= end);
  if (have) loadblk(i, sc_, wc_);
  while (have){
    float x[8];
    #pragma unroll
    for (int j = 0; j < 8; j++){
      const unsigned short* rp = xl + (size_t)sc_[j]*64;
      x[j] = bf2f(rp[lane]);
    }
    bool hnext = (i + 16 <= end);
    int sn_[8]; float wn_[8];
    if (hnext) loadblk(i + 8, sn_, wn_);

    float pp[8];
    #pragma unroll
    for (int j = 0; j < 8; j++){
      float t = fmaf(wc_[j], we0, fxr0) + x[j];
      float p = fmaf(c1, t, c2*fabsf(t));
      pp[j] = sum64(p, bpa);
    }
    float mx = fmaxf(fmaxf(fmaxf(pp[0], pp[1]), fmaxf(pp[2], pp[3])),
                     fmaxf(fmaxf(pp[4], pp[5]), fmaxf(pp[6], pp[7])));
    float nm = fmaxf(m, mx);
    float sc = exp2f(m - nm);
    float el = 0.f, ea = 0.f;
    #pragma unroll
    for (int j = 0; j < 8; j++){
      float e = exp2f(pp[j] - nm);
      el += e;
      ea += e*x[j];
    }
    l  = l*sc  + el;
    a0 = a0*sc + ea;
    m = nm;
    i += 8;
    have = hnext;
    if (have){
      #pragma unroll
      for (int j = 0; j < 8; j++){ sc_[j] = sn_[j]; wc_[j] = wn_[j]; }
    }
  }
  for (; i < end; i++){
    uint2 pk = csr[i];
    int sv = (int)pk.x;
    if ((unsigned)sv >= (unsigned)n) sv = 0;
    float w = __builtin_bit_cast(float, pk.y);
    float x0 = bf2f(xl[(size_t)sv*64 + lane]);
    float t0 = fmaf(w, we0, fxr0) + x0;
    float p  = fmaf(c1, t0, c2*fabsf(t0));
    p = sum64(p, bpa);
    float nm = fmaxf(m, p);
    float scv = exp2f(m - nm);
    float pe  = exp2f(p - nm);
    l  = l*scv  + pe;
    a0 = a0*scv + pe*x0;
    m = nm;
  }
  float inv = 1.0f / (l + 1e-16f);
  float res = a0*inv + bias[lane];
  size_t oi = (size_t)node*64 + lane;
  if (flag[0]) ((float*)out)[oi] = res;
  else         ((unsigned short*)out)[oi] = f2bf(res);
}

// ---------------- host ----------------

extern "C" void kernel_launch(void* const* d_in, const int* in_sizes, int n_in,
                              void* d_out, int out_size, void* d_ws, size_t ws_size,
                              hipStream_t stream)
{
  (void)n_in; (void)out_size; (void)ws_size;
  const void* x   = d_in[0];
  const int*  ei  = (const int*)d_in[1];
  const void* ew  = d_in[2];

  const int N = in_sizes[0] / 128;
  const int E = in_sizes[2];
  const int ET = E + N;
  const int nB = (N + 255) / 256;

  char* p = (char*)d_ws;
  size_t off = 0;
  auto carve = [&](size_t bytes)->void* {
    void* r = p + off;
    off = (off + bytes + 255) & ~(size_t)255;
    return r;
  };
  int*                flag   = (int*)carve(4);
  unsigned long long* acc    = (unsigned long long*)carve((size_t)N*NREP*8); // 64B/node
  uint4*              pso    = (uint4*)carve((size_t)N*16);
  int*                rowptr = (int*)carve((size_t)(N+1)*4);
  int*                bsum   = (int*)carve((size_t)nB*4);
  int*                rank   = (int*)carve((size_t)E*4);
  uint2*              csr    = (uint2*)carve((size_t)ET*8);
  float*              prm    = (float*)carve(15*128*4);
  unsigned short*     WT0l   = (unsigned short*)carve(128*128*2);
  unsigned short*     WT0r   = (unsigned short*)carve(128*128*2);
  unsigned short*     WT1l   = (unsigned short*)carve(128*128*2);
  unsigned short*     WT1r   = (unsigned short*)carve(128*128*2);
  unsigned short*     WT2l   = (unsigned short*)carve(128*64*2);
  unsigned short*     WT2r   = (unsigned short*)carve(128*64*2);
  unsigned short*     xlb16  = (unsigned short*)carve((size_t)N*128*2);
  float*              xrb    = (float*)carve((size_t)N*128*4);
  unsigned short*     hb     = (unsigned short*)carve((size_t)N*128*2);

  float* bl0c = prm + 0*128;  float* br0c = prm + 1*128;
  float* We0c = prm + 2*128;  float* at0c = prm + 3*128;  float* bi0c = prm + 4*128;
  float* bl1c = prm + 5*128;  float* br1c = prm + 6*128;
  float* We1c = prm + 7*128;  float* at1c = prm + 8*128;  float* bi1c = prm + 9*128;
  float* bl2c = prm + 10*128; float* br2c = prm + 11*128;
  float* We2c = prm + 12*128; float* at2c = prm + 13*128; float* bi2c = prm + 14*128;

  const float LOG2E = 1.4426950408889634f;
  MegaArgs ma;
  {
    const void* srcs[15] = { d_in[4], d_in[6], d_in[7], d_in[8], d_in[9],
                             d_in[11], d_in[13], d_in[14], d_in[15], d_in[16],
                             d_in[18], d_in[20], d_in[21], d_in[22], d_in[23] };
    float* dsts[15] = { bl0c, br0c, We0c, at0c, bi0c,
                        bl1c, br1c, We1c, at1c, bi1c,
                        bl2c, br2c, We2c, at2c, bi2c };
    int ns[15] = {128,128,128,128,128, 128,128,128,128,128, 64,64,64,64,64};
    for (int i = 0; i < 15; i++){
      ma.psrc[i] = srcs[i]; ma.pdst[i] = dsts[i]; ma.pn[i] = ns[i];
      ma.pscale[i] = (i == 3 || i == 8 || i == 13) ? LOG2E : 1.0f;  // att slots
    }
    const void* wsrcs[6] = { d_in[3], d_in[5], d_in[10], d_in[12], d_in[17], d_in[19] };
    unsigned short* wdsts[6] = { WT0l, WT0r, WT1l, WT1r, WT2l, WT2r };
    int Ms[6] = {128, 128, 128, 128, 64, 64};
    for (int i = 0; i < 6; i++){ ma.wsrc[i] = wsrcs[i]; ma.wdst[i] = wdsts[i]; ma.wM[i] = Ms[i]; }
    ma.x = x;
    ma.cnt = (int*)acc; ma.nz4 = N*4;   // N*64 bytes in int4 granules
    ma.flag = flag;
  }
  int zB = (ma.nz4 + 255) / 256;
  k_mega<<<1 + 320 + zB, 256, 0, stream>>>(ma);

  // graph build + layer-0 GEMM fused (gemm reads x directly, flag-branched)
  const int Eb = (E + 255) / 256;
  const int rowBlocks = (N + 15) / 16;
  const int gB = (2*rowBlocks + 3) / 4;
  k_histgemm<<<gB + Eb, 256, 0, stream>>>(x, WT0l, WT0r, bl0c, br0c, xlb16, xrb,
                                          N, rowBlocks, gB,
                                          ei, ew, acc, rank, E, N, flag);

  // cooperative fused scan (replaces scan1 + scan3, one launch gap saved)
  {
    const unsigned long long* acc_ = acc;
    int* bsum_ = bsum; int* rowptr_ = rowptr; uint4* pso_ = pso;
    int n_ = N, nb_ = nB;
    void* args[] = { (void*)&acc_, (void*)&bsum_, (void*)&rowptr_, (void*)&pso_,
                     (void*)&n_, (void*)&nb_ };
    hipLaunchCooperativeKernel((void*)k_scanc, dim3(nB), dim3(256), args, 0, stream);
  }

  k_scat_self<<<Eb + nB, 256, 0, stream>>>(ei, ew, rank, rowptr, acc, pso, csr,
                                           E, N, ET, flag, Eb, gB);

  // layer 0 edge (gemm0 already done in k_histgemm)
  k_edge128<<<(N+3)/4, 256, 0, stream>>>(xlb16, xrb, rowptr, csr, We0c, at0c, bi0c, hb, N, ET);

  // layer 1
  k_gemm2<128><<<dim3(rowBlocks, 2), 64, 0, stream>>>(hb, WT1l, WT1r, bl1c, br1c, xlb16, xrb, N);
  k_edge128<<<(N+3)/4, 256, 0, stream>>>(xlb16, xrb, rowptr, csr, We1c, at1c, bi1c, hb, N, ET);

  // layer 2
  k_gemm2<64><<<dim3(rowBlocks, 2), 64, 0, stream>>>(hb, WT2l, WT2r, bl2c, br2c, xlb16, xrb, N);
  k_edge64<<<(N+3)/4, 256, 0, stream>>>(xlb16, xrb, rowptr, csr, We2c, at2c, bi2c,
                                        d_out, N, ET, flag);
}

// Round 11
// 407.214 us; speedup vs baseline: 1.1697x; 1.1697x over previous
//
#include <hip/hip_runtime.h>
#include <cstdint>
#include <cstddef>

typedef __bf16 bf16x8 __attribute__((ext_vector_type(8)));
typedef float f32x4 __attribute__((ext_vector_type(4)));

__device__ __forceinline__ float bf2f(unsigned short u){
  unsigned int x = ((unsigned int)u) << 16;
  return __builtin_bit_cast(float, x);
}
__device__ __forceinline__ unsigned short f2bf(float f){
  unsigned int x = __builtin_bit_cast(unsigned int, f);
  x += 0x7fffu + ((x >> 16) & 1u);
  return (unsigned short)(x >> 16);
}

// ---- cross-lane reductions on the (idle) LDS pipe: ds_swizzle butterflies ----
template<int P> __device__ __forceinline__ float swz_add(float x){
  int y = __builtin_amdgcn_ds_swizzle(__builtin_bit_cast(int, x), P);
  return x + __builtin_bit_cast(float, y);
}
__device__ __forceinline__ float sum16(float x){
  x = swz_add<0x041F>(x);   // xor 1  (BitMode: and=0x1F, or=0, xor=k)
  x = swz_add<0x081F>(x);   // xor 2
  x = swz_add<0x101F>(x);   // xor 4
  x = swz_add<0x201F>(x);   // xor 8
  return x;
}
__device__ __forceinline__ float sum64(float x, int bpa){
  x = swz_add<0x041F>(x);
  x = swz_add<0x081F>(x);
  x = swz_add<0x101F>(x);
  x = swz_add<0x201F>(x);
  x = swz_add<0x401F>(x);   // xor 16 (within 32-lane group)
  int y = __builtin_amdgcn_ds_bpermute(bpa, __builtin_bit_cast(int, x)); // lane^32
  return x + __builtin_bit_cast(float, y);
}

__device__ __forceinline__ float load_w(const void* ew, int e, int f){
  return f ? ((const float*)ew)[e] : bf2f(((const unsigned short*)ew)[e]);
}

// fixed-point packing for the 64b atomic (per-XCD replica):
//   acc[d*NREP + rep] += (1<<40) | round(w * 2^24)
// high 24 bits = replica count (old>>40 == replica-local rank), low 40 = wsum.
// NOTE (r5/r7/r8/r9): padding, addr-sharding, MLPx4, XCD replicas ALL null ->
// ~12 G returning-RMW/s is the memory-side atomic floor. Build path closed.
// NOTE (r10): hipLaunchCooperativeKernel cost ~60us/iter in this harness
// (graph-capture hostile) -> launch-gap attacks must use block-range fusion.
#define WSUM_MASK  ((1ull << 40) - 1ull)
#define WSUM_SCALE 16777216.0f
#define WSUM_INV   (1.0f / 16777216.0f)
#define NREP 8

// ---------------- mega canon kernel ----------------
// xc canon deleted (r10, counters cleared it): gemm0 reads x directly.
// Block ranges: [0] params+flag; [1,321) weight transpose; [321,..) acc zero.

struct MegaArgs {
  const void* psrc[15]; float* pdst[15]; int pn[15]; float pscale[15];
  const void* wsrc[6]; unsigned short* wdst[6]; int wM[6];
  const void* x;
  int* cnt; int nz4;
  int* flag;
};

__global__ __launch_bounds__(256) void k_mega(MegaArgs a){
  __shared__ int sf;
  if (threadIdx.x == 0) sf = 0;
  __syncthreads();
  {
    unsigned short u = ((const unsigned short*)a.x)[threadIdx.x];
    int expo = (u >> 7) & 0xFF;
    if (expo >= 0xC0) atomicOr(&sf, 1);
  }
  __syncthreads();
  int f = sf;
  int b = blockIdx.x;

  if (b == 0){
    if (threadIdx.x == 0) a.flag[0] = f;
    for (int t = 0; t < 15; t++){
      int i = threadIdx.x;
      if (i < a.pn[t]){
        float v = f ? ((const float*)a.psrc[t])[i]
                    : bf2f(((const unsigned short*)a.psrc[t])[i]);
        a.pdst[t][i] = v * a.pscale[t];
      }
    }
    return;
  }
  b -= 1;
  if (b < 320){
    int t, base;
    if      (b <  64){ t = 0; base = b;       }
    else if (b < 128){ t = 1; base = b - 64;  }
    else if (b < 192){ t = 2; base = b - 128; }
    else if (b < 256){ t = 3; base = b - 192; }
    else if (b < 288){ t = 4; base = b - 256; }
    else             { t = 5; base = b - 288; }
    int M = a.wM[t];
    int idx = base*256 + threadIdx.x;
    if (idx < 128*M){
      int k = idx / M, m2 = idx % M;
      unsigned short v = f ? f2bf(((const float*)a.wsrc[t])[idx])
                           : ((const unsigned short*)a.wsrc[t])[idx];
      a.wdst[t][m2*128 + k] = v;
    }
    return;
  }
  b -= 320;
  int i = b*256 + threadIdx.x;
  if (i < a.nz4) ((int4*)a.cnt)[i] = make_int4(0, 0, 0, 0);
}

// ---------------- fused: layer-0 GEMM (reads x directly) + hist ----------------
// blocks [0, gB): gemm layer-0 (4 row-tile waves per block, L+R halves);
// blocks [gB, ..): hist, 1 edge/thread, replica = blockIdx & 7.

__global__ __launch_bounds__(256) void k_histgemm(
  const void* __restrict__ X,
  const unsigned short* __restrict__ WTl, const unsigned short* __restrict__ WTr,
  const float* __restrict__ bl, const float* __restrict__ br,
  unsigned short* __restrict__ outL, float* __restrict__ outR,
  int nrows, int rowBlocks, int gB,
  const int* __restrict__ ei, const void* __restrict__ ew,
  unsigned long long* __restrict__ acc,
  int* __restrict__ rank, int E, int n, const int* __restrict__ flag)
{
  int b = blockIdx.x;
  if (b < gB){
    int wid = threadIdx.x >> 6;
    int t = b*4 + wid;
    if (t >= 2*rowBlocks) return;
    bool isR = t >= rowBlocks;
    int r0 = (isR ? t - rowBlocks : t) * 16;
    const unsigned short* WT = isR ? WTr : WTl;
    const float* bia         = isR ? br  : bl;
    int lane = threadIdx.x & 63;
    int q = lane >> 4, rr = lane & 15;
    int xf = flag[0];

    f32x4 ac[8];
    #pragma unroll
    for (int c = 0; c < 8; c++) ac[c] = (f32x4){0.f, 0.f, 0.f, 0.f};
    int row = r0 + rr;
    if (row >= nrows) row = nrows - 1;
    #pragma unroll
    for (int kc = 0; kc < 4; kc++){
      bf16x8 af;
      if (xf){
        const float* xp = (const float*)X + (size_t)row*128 + kc*32 + q*8;
        float4 lo = *(const float4*)xp;
        float4 hi = *(const float4*)(xp + 4);
        unsigned short t8[8] = { f2bf(lo.x), f2bf(lo.y), f2bf(lo.z), f2bf(lo.w),
                                 f2bf(hi.x), f2bf(hi.y), f2bf(hi.z), f2bf(hi.w) };
        __builtin_memcpy(&af, t8, 16);
      } else {
        af = *(const bf16x8*)((const unsigned short*)X + (size_t)row*128 + kc*32 + q*8);
      }
      #pragma unroll
      for (int ct = 0; ct < 8; ct++){
        bf16x8 bfr = *(const bf16x8*)(WT + (size_t)(ct*16 + rr)*128 + kc*32 + q*8);
        ac[ct] = __builtin_amdgcn_mfma_f32_16x16x32_bf16(af, bfr, ac[ct], 0, 0, 0);
      }
    }
    #pragma unroll
    for (int ct = 0; ct < 8; ct++){
      int col = ct*16 + rr;
      float bv = bia[col];
      #pragma unroll
      for (int t4 = 0; t4 < 4; t4++){
        int orow = r0 + q*4 + t4;
        if (orow < nrows){
          float v = ac[ct][t4] + bv;
          if (isR) outR[(size_t)orow*128 + col] = v;
          else     outL[(size_t)orow*128 + col] = f2bf(v);
        }
      }
    }
    return;
  }
  int e = (b - gB)*256 + threadIdx.x;
  if (e < E){
    int d = ei[E + e];
    int r = 0;
    if ((unsigned)d < (unsigned)n){
      float w = load_w(ew, e, flag[0]);
      unsigned int wq = (unsigned int)(w * WSUM_SCALE + 0.5f);
      unsigned long long pk = (1ull << 40) | (unsigned long long)wq;
      int rep = b & (NREP - 1);    // == ((e>>8) + gB) & 7, recomputed in scatter
      unsigned long long old = atomicAdd(&acc[(size_t)d*NREP + rep], pk);
      r = (int)(old >> 40);
    }
    rank[e] = r;
  }
}

__global__ void k_scan1(const unsigned long long* __restrict__ acc,
                        int* __restrict__ bsum, int n){
  int i = blockIdx.x*256 + threadIdx.x;
  int lane = threadIdx.x & 63, w = threadIdx.x >> 6;
  int v = 0;
  if (i < n){
    const unsigned long long* a = acc + (size_t)i*NREP;
    int s = 0;
    #pragma unroll
    for (int r = 0; r < NREP; r++) s += (int)(a[r] >> 40);
    v = s + 1;
  }
  for (int off = 32; off; off >>= 1) v += __shfl_down(v, off);
  __shared__ int ws[4];
  if (lane == 0) ws[w] = v;
  __syncthreads();
  if (threadIdx.x == 0) bsum[blockIdx.x] = ws[0] + ws[1] + ws[2] + ws[3];
}

// fused scan phases 2+3; also emits per-node replica prefix (pso, 8x ushort)
__global__ void k_scan3(const unsigned long long* __restrict__ acc,
                        const int* __restrict__ bsum,
                        int* __restrict__ rowptr, uint4* __restrict__ pso,
                        int n, int nB){
  int b = blockIdx.x, tid = threadIdx.x;
  int lane = tid & 63, w = tid >> 6;
  __shared__ int ws[4];
  __shared__ int sboff;

  int part = 0;
  for (int t = tid; t < b; t += 256) part += bsum[t];
  for (int off = 32; off; off >>= 1) part += __shfl_down(part, off);
  if (lane == 0) ws[w] = part;
  __syncthreads();
  if (tid == 0) sboff = ws[0] + ws[1] + ws[2] + ws[3];
  __syncthreads();
  int boff = sboff;
  __syncthreads();

  int i = b*256 + tid;
  int v = 0;
  if (i < n){
    const unsigned long long* a = acc + (size_t)i*NREP;
    int c[NREP], s = 0;
    unsigned short pf[NREP];
    #pragma unroll
    for (int r = 0; r < NREP; r++){
      c[r] = (int)(a[r] >> 40);
      pf[r] = (unsigned short)s;
      s += c[r];
    }
    v = s + 1;
    uint4 o;
    o.x = (unsigned)pf[0] | ((unsigned)pf[1] << 16);
    o.y = (unsigned)pf[2] | ((unsigned)pf[3] << 16);
    o.z = (unsigned)pf[4] | ((unsigned)pf[5] << 16);
    o.w = (unsigned)pf[6] | ((unsigned)pf[7] << 16);
    pso[i] = o;
  }
  int sv = v;
  for (int off = 1; off < 64; off <<= 1){
    int t = __shfl_up(sv, off);
    if (lane >= off) sv += t;
  }
  if (lane == 63) ws[w] = sv;
  __syncthreads();
  if (tid == 0){
    int acc2 = 0;
    for (int k = 0; k < 4; k++){ int t = ws[k]; ws[k] = acc2; acc2 += t; }
  }
  __syncthreads();
  if (i < n) rowptr[i + 1] = boff + ws[w] + sv;
  if (i == 0) rowptr[0] = 0;
  (void)nB;
}

// fused: ATOMIC-FREE scatter (blocks [0,Eb)) + self-loop write (blocks [Eb,..)).
// pos = rowptr[d] + replicaPrefix[d][rep] + replica-local rank,
// rep = ((e>>8) + gB) & 7 (same formula as hist).
__global__ void k_scat_self(const int* __restrict__ ei, const void* __restrict__ ew,
                            const int* __restrict__ rank, const int* __restrict__ rowptr,
                            const unsigned long long* __restrict__ acc,
                            const uint4* __restrict__ pso,
                            uint2* __restrict__ csr,
                            int E, int n, int ET, const int* __restrict__ flag,
                            int Eb, int gB){
  int b = blockIdx.x;
  if (b < Eb){
    int e = b*256 + threadIdx.x;
    if (e < E){
      int s = ei[e], d = ei[E + e];
      if ((unsigned)d < (unsigned)n){
        int rep = ((e >> 8) + gB) & (NREP - 1);
        uint4 ps = pso[d];
        unsigned word = (rep < 4) ? ((rep < 2) ? ps.x : ps.y)
                                  : ((rep < 6) ? ps.z : ps.w);
        unsigned pref = (word >> ((rep & 1) * 16)) & 0xffffu;
        int pos = rowptr[d] + (int)pref + rank[e];
        if ((unsigned)pos < (unsigned)ET){
          float w = load_w(ew, e, flag[0]);
          csr[pos] = make_uint2((unsigned)s, __builtin_bit_cast(unsigned, w));
        }
      }
    }
  } else {
    int i = (b - Eb)*256 + threadIdx.x;
    if (i < n){
      int beg = rowptr[i], endv = rowptr[i+1];
      int deg = endv - 1 - beg;
      const unsigned long long* a = acc + (size_t)i*NREP;
      unsigned long long s = 0;
      #pragma unroll
      for (int r = 0; r < NREP; r++) s += (a[r] & WSUM_MASK);
      float ws = (float)s * WSUM_INV;
      float w = ws / fmaxf((float)deg, 1.0f);
      csr[endv - 1] = make_uint2((unsigned)i, __builtin_bit_cast(unsigned, w));
    }
  }
}

// ---------------- GEMM (layers 1,2): xl (bf16) and xr (f32) in one launch ----------------

template<int NC>
__global__ __launch_bounds__(64) void k_gemm2(
  const unsigned short* __restrict__ A,
  const unsigned short* __restrict__ WTl, const unsigned short* __restrict__ WTr,
  const float* __restrict__ bl, const float* __restrict__ br,
  unsigned short* __restrict__ outL, float* __restrict__ outR,
  int nrows)
{
  constexpr int CT = NC / 16;
  int lane = threadIdx.x;
  int q = lane >> 4, rr = lane & 15;
  int r0 = blockIdx.x * 16;
  bool isR = blockIdx.y == 1;
  const unsigned short* WT = isR ? WTr : WTl;
  const float* bia         = isR ? br  : bl;

  f32x4 acc[CT];
  #pragma unroll
  for (int b = 0; b < CT; b++) acc[b] = (f32x4){0.f, 0.f, 0.f, 0.f};

  int row = r0 + rr;
  if (row >= nrows) row = nrows - 1;

  #pragma unroll
  for (int kc = 0; kc < 4; kc++){
    bf16x8 af = *(const bf16x8*)(A + (size_t)row*128 + kc*32 + q*8);
    #pragma unroll
    for (int ct = 0; ct < CT; ct++){
      bf16x8 bfr = *(const bf16x8*)(WT + (size_t)(ct*16 + rr)*128 + kc*32 + q*8);
      acc[ct] = __builtin_amdgcn_mfma_f32_16x16x32_bf16(af, bfr, acc[ct], 0, 0, 0);
    }
  }

  // C/D layout: col = lane&15, row = (lane>>4)*4 + reg
  #pragma unroll
  for (int ct = 0; ct < CT; ct++){
    int col = ct*16 + rr;
    float bv = bia[col];
    #pragma unroll
    for (int t = 0; t < 4; t++){
      int orow = r0 + q*4 + t;
      if (orow < nrows){
        float v = acc[ct][t] + bv;
        if (isR) outR[(size_t)orow*NC + col] = v;
        else     outL[(size_t)orow*NC + col] = f2bf(v);
      }
    }
  }
}

// ---------------- fused edge scoring + online-softmax aggregation ----------------
// [round-3/5 proven bodies] readfirstlane-scalarized csr fetch, |t| leakyrelu
// fold, ds_swizzle reductions, 8-edge SGPR block prefetch.

__global__ __launch_bounds__(256) void k_edge128(
  const unsigned short* __restrict__ xl, const float* __restrict__ xr,
  const int* __restrict__ rowptr, const uint2* __restrict__ csr,
  const float* __restrict__ We, const float* __restrict__ att,
  const float* __restrict__ bias, unsigned short* __restrict__ out, int n, int ET)
{
  int wid = threadIdx.x >> 6;
  int lane = threadIdx.x & 63;
  int node = __builtin_amdgcn_readfirstlane(blockIdx.x*4 + wid);
  if (node >= n) return;
  int ch = lane*2;
  float we0 = We[ch],  we1 = We[ch+1];
  float at0 = att[ch], at1 = att[ch+1];   // pre-scaled by log2e
  float c10 = 0.6f*at0, c20 = 0.4f*at0;
  float c11 = 0.6f*at1, c21 = 0.4f*at1;
  float2 xrv = *(const float2*)(xr + (size_t)node*128 + ch);
  float fxr0 = xrv.x, fxr1 = xrv.y;
  int beg = rowptr[node], end = rowptr[node+1];
  if (beg < 0) beg = 0;
  if (end > ET) end = ET;
  float m = -1e30f, l = 0.f, a0 = 0.f, a1 = 0.f;

  auto loadblk = [&](int base, int* S, float* W){
    #pragma unroll
    for (int j = 0; j < 8; j++){
      uint2 pk = csr[base + j];          // uniform addr -> s_load
      int sv = (int)pk.x;
      if ((unsigned)sv >= (unsigned)n) sv = 0;
      S[j] = sv;
      W[j] = __builtin_bit_cast(float, pk.y);
    }
  };

  int i = beg;
  int sc_[8]; float wc_[8];
  bool have = (i + 8 <= end);
  if (have) loadblk(i, sc_, wc_);
  while (have){
    unsigned u[8];
    #pragma unroll
    for (int j = 0; j < 8; j++){
      const unsigned short* rp = xl + (size_t)sc_[j]*128;   // scalar base
      u[j] = *(const unsigned int*)(rp + ch);               // saddr + v_ch
    }
    bool hnext = (i + 16 <= end);
    int sn_[8]; float wn_[8];
    if (hnext) loadblk(i + 8, sn_, wn_);    // prefetch next block

    float vx[8], vy[8], pp[8];
    #pragma unroll
    for (int j = 0; j < 8; j++){
      vx[j] = __builtin_bit_cast(float, u[j] << 16);
      vy[j] = __builtin_bit_cast(float, u[j] & 0xffff0000u);
      float t0 = fmaf(wc_[j], we0, fxr0) + vx[j];
      float t1 = fmaf(wc_[j], we1, fxr1) + vy[j];
      float p  = fmaf(c10, t0, c20*fabsf(t0));
      p        = fmaf(c11, t1, fmaf(c21, fabsf(t1), p));
      pp[j] = sum16(p);
    }
    float mx = fmaxf(fmaxf(fmaxf(pp[0], pp[1]), fmaxf(pp[2], pp[3])),
                     fmaxf(fmaxf(pp[4], pp[5]), fmaxf(pp[6], pp[7])));
    float nm = fmaxf(m, mx);
    float sc = exp2f(m - nm);
    float el = 0.f, ea0 = 0.f, ea1 = 0.f;
    #pragma unroll
    for (int j = 0; j < 8; j++){
      float e = exp2f(pp[j] - nm);
      el  += e;
      ea0 += e*vx[j];
      ea1 += e*vy[j];
    }
    l  = l*sc  + el;
    a0 = a0*sc + ea0;
    a1 = a1*sc + ea1;
    m = nm;
    i += 8;
    have = hnext;
    if (have){
      #pragma unroll
      for (int j = 0; j < 8; j++){ sc_[j] = sn_[j]; wc_[j] = wn_[j]; }
    }
  }
  for (; i < end; i++){
    uint2 pk = csr[i];
    int sv = (int)pk.x;
    if ((unsigned)sv >= (unsigned)n) sv = 0;
    float w = __builtin_bit_cast(float, pk.y);
    const unsigned short* rp = xl + (size_t)sv*128;
    unsigned u = *(const unsigned int*)(rp + ch);
    float x0 = __builtin_bit_cast(float, u << 16);
    float x1 = __builtin_bit_cast(float, u & 0xffff0000u);
    float t0 = fmaf(w, we0, fxr0) + x0;
    float t1 = fmaf(w, we1, fxr1) + x1;
    float p  = fmaf(c10, t0, c20*fabsf(t0));
    p        = fmaf(c11, t1, fmaf(c21, fabsf(t1), p));
    p = sum16(p);
    float nm = fmaxf(m, p);
    float scv = exp2f(m - nm);
    float pe  = exp2f(p - nm);
    l  = l*scv  + pe;
    a0 = a0*scv + pe*x0;
    a1 = a1*scv + pe*x1;
    m = nm;
  }
  float inv = 1.0f / (l + 1e-16f);
  float o0 = a0*inv + bias[ch];
  float o1 = a1*inv + bias[ch+1];
  o0 = o0 > 0.f ? o0 : (__expf(o0) - 1.0f);   // ELU (layers 0,1)
  o1 = o1 > 0.f ? o1 : (__expf(o1) - 1.0f);
  unsigned int packed = (unsigned int)f2bf(o0) | ((unsigned int)f2bf(o1) << 16);
  *(unsigned int*)(out + (size_t)node*128 + ch) = packed;
}

__global__ __launch_bounds__(256) void k_edge64(
  const unsigned short* __restrict__ xl, const float* __restrict__ xr,
  const int* __restrict__ rowptr, const uint2* __restrict__ csr,
  const float* __restrict__ We, const float* __restrict__ att,
  const float* __restrict__ bias, void* __restrict__ out, int n, int ET,
  const int* __restrict__ flag)
{
  int wid = threadIdx.x >> 6;
  int lane = threadIdx.x & 63;
  int node = __builtin_amdgcn_readfirstlane(blockIdx.x*4 + wid);
  if (node >= n) return;
  float we0 = We[lane];
  float at0 = att[lane];          // pre-scaled by log2e
  float c1 = 0.6f*at0, c2 = 0.4f*at0;
  float fxr0 = xr[(size_t)node*64 + lane];
  int bpa = ((lane ^ 32) << 2);
  int beg = rowptr[node], end = rowptr[node+1];
  if (beg < 0) beg = 0;
  if (end > ET) end = ET;
  float m = -1e30f, l = 0.f, a0 = 0.f;

  auto loadblk = [&](int base, int* S, float* W){
    #pragma unroll
    for (int j = 0; j < 8; j++){
      uint2 pk = csr[base + j];
      int sv = (int)pk.x;
      if ((unsigned)sv >= (unsigned)n) sv = 0;
      S[j] = sv;
      W[j] = __builtin_bit_cast(float, pk.y);
    }
  };

  int i = beg;
  int sc_[8]; float wc_[8];
  bool have = (i + 8 <= end);
  if (have) loadblk(i, sc_, wc_);
  while (have){
    float x[8];
    #pragma unroll
    for (int j = 0; j < 8; j++){
      const unsigned short* rp = xl + (size_t)sc_[j]*64;
      x[j] = bf2f(rp[lane]);
    }
    bool hnext = (i + 16 <= end);
    int sn_[8]; float wn_[8];
    if (hnext) loadblk(i + 8, sn_, wn_);

    float pp[8];
    #pragma unroll
    for (int j = 0; j < 8; j++){
      float t = fmaf(wc_[j], we0, fxr0) + x[j];
      float p = fmaf(c1, t, c2*fabsf(t));
      pp[j] = sum64(p, bpa);
    }
    float mx = fmaxf(fmaxf(fmaxf(pp[0], pp[1]), fmaxf(pp[2], pp[3])),
                     fmaxf(fmaxf(pp[4], pp[5]), fmaxf(pp[6], pp[7])));
    float nm = fmaxf(m, mx);
    float sc = exp2f(m - nm);
    float el = 0.f, ea = 0.f;
    #pragma unroll
    for (int j = 0; j < 8; j++){
      float e = exp2f(pp[j] - nm);
      el += e;
      ea += e*x[j];
    }
    l  = l*sc  + el;
    a0 = a0*sc + ea;
    m = nm;
    i += 8;
    have = hnext;
    if (have){
      #pragma unroll
      for (int j = 0; j < 8; j++){ sc_[j] = sn_[j]; wc_[j] = wn_[j]; }
    }
  }
  for (; i < end; i++){
    uint2 pk = csr[i];
    int sv = (int)pk.x;
    if ((unsigned)sv >= (unsigned)n) sv = 0;
    float w = __builtin_bit_cast(float, pk.y);
    float x0 = bf2f(xl[(size_t)sv*64 + lane]);
    float t0 = fmaf(w, we0, fxr0) + x0;
    float p  = fmaf(c1, t0, c2*fabsf(t0));
    p = sum64(p, bpa);
    float nm = fmaxf(m, p);
    float scv = exp2f(m - nm);
    float pe  = exp2f(p - nm);
    l  = l*scv  + pe;
    a0 = a0*scv + pe*x0;
    m = nm;
  }
  float inv = 1.0f / (l + 1e-16f);
  float res = a0*inv + bias[lane];
  size_t oi = (size_t)node*64 + lane;
  if (flag[0]) ((float*)out)[oi] = res;
  else         ((unsigned short*)out)[oi] = f2bf(res);
}

// ---------------- host ----------------

extern "C" void kernel_launch(void* const* d_in, const int* in_sizes, int n_in,
                              void* d_out, int out_size, void* d_ws, size_t ws_size,
                              hipStream_t stream)
{
  (void)n_in; (void)out_size; (void)ws_size;
  const void* x   = d_in[0];
  const int*  ei  = (const int*)d_in[1];
  const void* ew  = d_in[2];

  const int N = in_sizes[0] / 128;
  const int E = in_sizes[2];
  const int ET = E + N;
  const int nB = (N + 255) / 256;

  char* p = (char*)d_ws;
  size_t off = 0;
  auto carve = [&](size_t bytes)->void* {
    void* r = p + off;
    off = (off + bytes + 255) & ~(size_t)255;
    return r;
  };
  int*                flag   = (int*)carve(4);
  unsigned long long* acc    = (unsigned long long*)carve((size_t)N*NREP*8); // 64B/node
  uint4*              pso    = (uint4*)carve((size_t)N*16);
  int*                rowptr = (int*)carve((size_t)(N+1)*4);
  int*                bsum   = (int*)carve((size_t)nB*4);
  int*                rank   = (int*)carve((size_t)E*4);
  uint2*              csr    = (uint2*)carve((size_t)ET*8);
  float*              prm    = (float*)carve(15*128*4);
  unsigned short*     WT0l   = (unsigned short*)carve(128*128*2);
  unsigned short*     WT0r   = (unsigned short*)carve(128*128*2);
  unsigned short*     WT1l   = (unsigned short*)carve(128*128*2);
  unsigned short*     WT1r   = (unsigned short*)carve(128*128*2);
  unsigned short*     WT2l   = (unsigned short*)carve(128*64*2);
  unsigned short*     WT2r   = (unsigned short*)carve(128*64*2);
  unsigned short*     xlb16  = (unsigned short*)carve((size_t)N*128*2);
  float*              xrb    = (float*)carve((size_t)N*128*4);
  unsigned short*     hb     = (unsigned short*)carve((size_t)N*128*2);

  float* bl0c = prm + 0*128;  float* br0c = prm + 1*128;
  float* We0c = prm + 2*128;  float* at0c = prm + 3*128;  float* bi0c = prm + 4*128;
  float* bl1c = prm + 5*128;  float* br1c = prm + 6*128;
  float* We1c = prm + 7*128;  float* at1c = prm + 8*128;  float* bi1c = prm + 9*128;
  float* bl2c = prm + 10*128; float* br2c = prm + 11*128;
  float* We2c = prm + 12*128; float* at2c = prm + 13*128; float* bi2c = prm + 14*128;

  const float LOG2E = 1.4426950408889634f;
  MegaArgs ma;
  {
    const void* srcs[15] = { d_in[4], d_in[6], d_in[7], d_in[8], d_in[9],
                             d_in[11], d_in[13], d_in[14], d_in[15], d_in[16],
                             d_in[18], d_in[20], d_in[21], d_in[22], d_in[23] };
    float* dsts[15] = { bl0c, br0c, We0c, at0c, bi0c,
                        bl1c, br1c, We1c, at1c, bi1c,
                        bl2c, br2c, We2c, at2c, bi2c };
    int ns[15] = {128,128,128,128,128, 128,128,128,128,128, 64,64,64,64,64};
    for (int i = 0; i < 15; i++){
      ma.psrc[i] = srcs[i]; ma.pdst[i] = dsts[i]; ma.pn[i] = ns[i];
      ma.pscale[i] = (i == 3 || i == 8 || i == 13) ? LOG2E : 1.0f;  // att slots
    }
    const void* wsrcs[6] = { d_in[3], d_in[5], d_in[10], d_in[12], d_in[17], d_in[19] };
    unsigned short* wdsts[6] = { WT0l, WT0r, WT1l, WT1r, WT2l, WT2r };
    int Ms[6] = {128, 128, 128, 128, 64, 64};
    for (int i = 0; i < 6; i++){ ma.wsrc[i] = wsrcs[i]; ma.wdst[i] = wdsts[i]; ma.wM[i] = Ms[i]; }
    ma.x = x;
    ma.cnt = (int*)acc; ma.nz4 = N*4;   // N*64 bytes in int4 granules
    ma.flag = flag;
  }
  int zB = (ma.nz4 + 255) / 256;
  k_mega<<<1 + 320 + zB, 256, 0, stream>>>(ma);

  // graph build + layer-0 GEMM fused (gemm reads x directly, flag-branched)
  const int Eb = (E + 255) / 256;
  const int rowBlocks = (N + 15) / 16;
  const int gB = (2*rowBlocks + 3) / 4;
  k_histgemm<<<gB + Eb, 256, 0, stream>>>(x, WT0l, WT0r, bl0c, br0c, xlb16, xrb,
                                          N, rowBlocks, gB,
                                          ei, ew, acc, rank, E, N, flag);

  // scan (two plain launches — cooperative variant cost ~60us/iter, r10)
  k_scan1<<<nB, 256, 0, stream>>>(acc, bsum, N);
  k_scan3<<<nB, 256, 0, stream>>>(acc, bsum, rowptr, pso, N, nB);

  k_scat_self<<<Eb + nB, 256, 0, stream>>>(ei, ew, rank, rowptr, acc, pso, csr,
                                           E, N, ET, flag, Eb, gB);

  // layer 0 edge (gemm0 already done in k_histgemm)
  k_edge128<<<(N+3)/4, 256, 0, stream>>>(xlb16, xrb, rowptr, csr, We0c, at0c, bi0c, hb, N, ET);

  // layer 1
  k_gemm2<128><<<dim3(rowBlocks, 2), 64, 0, stream>>>(hb, WT1l, WT1r, bl1c, br1c, xlb16, xrb, N);
  k_edge128<<<(N+3)/4, 256, 0, stream>>>(xlb16, xrb, rowptr, csr, We1c, at1c, bi1c, hb, N, ET);

  // layer 2
  k_gemm2<64><<<dim3(rowBlocks, 2), 64, 0, stream>>>(hb, WT2l, WT2r, bl2c, br2c, xlb16, xrb, N);
  k_edge64<<<(N+3)/4, 256, 0, stream>>>(xlb16, xrb, rowptr, csr, We2c, at2c, bi2c,
                                        d_out, N, ET, flag);
}